// Round 11
// baseline (884.842 us; speedup 1.0000x reference)
//
#include <hip/hip_runtime.h>
#include <hip/hip_bf16.h>

// Decoder_21208548508049 — round 11: SPLIT kernels.
// r10 post-mortem: fused kernel ran phase A at only 8 waves/CU (phase B's
// 128-VGPR need) -> VALUBusy 36%, ~750us in phase A alone. Phase B is ~60us.
// Also: MFMA epilogue scalar stores = half-dirty 128B lines -> ~2x write amp.
// Fix: kernel A (GEMM1+LIF, 64 VGPR, 8KB LDS, up to 32 waves/CU) writes spike
// bitmask to global; kernel B (GEMM2 MFMA) reads it, stages C in LDS for
// coalesced 512B-row writes. All numerics bit-identical to r10 (absmax 0.03125).

#define TT 32
#define CH 8
#define BB 8
#define NN 256
#define DD 512

typedef __attribute__((ext_vector_type(8))) short short8;
typedef __attribute__((ext_vector_type(4))) float f32x4;

__device__ __forceinline__ unsigned short f2bf(float f) {
    __hip_bfloat16 h = __float2bfloat16(f);
    return *reinterpret_cast<unsigned short*>(&h);
}

// ---- pre-kernel: Wt[p][d] = bf16(Wr[d][p]) ----
__global__ void cast_transpose_wr(const float* __restrict__ Wr,
                                  unsigned short* __restrict__ Wt) {
    int idx = blockIdx.x * 256 + threadIdx.x;      // 0..262143
    int d = idx >> 9;
    int p = idx & 511;
    Wt[p * DD + d] = f2bf(Wr[idx]);
}

// ================= Kernel A: GEMM1 (exact f32) + LIF -> global bitmask =====
// 1 token/block, 128 threads, e0 = tid*4. x staged in d-halves (8KB LDS).
// fmaf chain per (t,e): bias-init, d-ascending — identical to r1/4/5/6/10.
__global__ __launch_bounds__(128, 4) void lif_phaseA(
    const float* __restrict__ x,      // [T,B,N,D]
    const float* __restrict__ tr_mx,  // [B,N,D]
    const float* __restrict__ Wl,     // [D,D]
    const float* __restrict__ bl,     // [D]
    unsigned* __restrict__ gmsk)      // [B*N, D] spike bits: (gmsk[tok*D+d]>>t)&1
{
    __shared__ __align__(16) float xs[CH * 256];   // 8 KB: t-chunk x d-half

    const int tid = threadIdx.x;          // 0..127
    const int tok = blockIdx.x;           // 0..2047
    const int e0  = tid * 4;
    const size_t base = (size_t)tok * DD;
    const size_t st   = (size_t)BB * NN * DD;

    float acc[CH][4];
    float4 m4 = *reinterpret_cast<const float4*>(&tr_mx[base + e0]);
    float m[4] = {m4.x, m4.y, m4.z, m4.w};
    unsigned mc[4] = {0u, 0u, 0u, 0u};

    const float4 blv = *reinterpret_cast<const float4*>(&bl[e0]);
    const float blr[4] = {blv.x, blv.y, blv.z, blv.w};

    #pragma unroll 1
    for (int tg = 0; tg < 4; ++tg) {
        #pragma unroll
        for (int i = 0; i < CH; ++i)
            #pragma unroll
            for (int e = 0; e < 4; ++e) acc[i][e] = blr[e];

        #pragma unroll 1
        for (int h = 0; h < 2; ++h) {
            // stage x[tg*8..+7][h*256..+255]: 4 float4/thread, coalesced
            #pragma unroll
            for (int r = 0; r < 4; ++r) {
                const int flat = r * 128 + tid;       // 0..511
                const int row  = flat >> 6;           // 0..7
                const int c4   = flat & 63;
                const float4 v = *reinterpret_cast<const float4*>(
                    &x[(size_t)(tg * CH + row) * st + base + h * 256 + c4 * 4]);
                *reinterpret_cast<float4*>(&xs[row * 256 + c4 * 4]) = v;
            }
            __syncthreads();

            #pragma unroll 2
            for (int dd_ = 0; dd_ < 256; dd_ += 4) {
                const int d = h * 256 + dd_;
                const float4 w0 = *reinterpret_cast<const float4*>(&Wl[(size_t)(d + 0) * DD + e0]);
                const float4 w1 = *reinterpret_cast<const float4*>(&Wl[(size_t)(d + 1) * DD + e0]);
                const float4 w2 = *reinterpret_cast<const float4*>(&Wl[(size_t)(d + 2) * DD + e0]);
                const float4 w3 = *reinterpret_cast<const float4*>(&Wl[(size_t)(d + 3) * DD + e0]);
                #pragma unroll
                for (int i = 0; i < CH; ++i) {
                    const float4 xv = *reinterpret_cast<const float4*>(&xs[i * 256 + dd_]);
                    acc[i][0] = fmaf(xv.x, w0.x, acc[i][0]);
                    acc[i][1] = fmaf(xv.x, w0.y, acc[i][1]);
                    acc[i][2] = fmaf(xv.x, w0.z, acc[i][2]);
                    acc[i][3] = fmaf(xv.x, w0.w, acc[i][3]);
                    acc[i][0] = fmaf(xv.y, w1.x, acc[i][0]);
                    acc[i][1] = fmaf(xv.y, w1.y, acc[i][1]);
                    acc[i][2] = fmaf(xv.y, w1.z, acc[i][2]);
                    acc[i][3] = fmaf(xv.y, w1.w, acc[i][3]);
                    acc[i][0] = fmaf(xv.z, w2.x, acc[i][0]);
                    acc[i][1] = fmaf(xv.z, w2.y, acc[i][1]);
                    acc[i][2] = fmaf(xv.z, w2.z, acc[i][2]);
                    acc[i][3] = fmaf(xv.z, w2.w, acc[i][3]);
                    acc[i][0] = fmaf(xv.w, w3.x, acc[i][0]);
                    acc[i][1] = fmaf(xv.w, w3.y, acc[i][1]);
                    acc[i][2] = fmaf(xv.w, w3.z, acc[i][2]);
                    acc[i][3] = fmaf(xv.w, w3.w, acc[i][3]);
                }
            }
            __syncthreads();   // xs reads done before next stage overwrites
        }

        // LIF for this chunk (identical arithmetic to all prior passes)
        #pragma unroll
        for (int i = 0; i < CH; ++i) {
            const int t = tg * CH + i;
            #pragma unroll
            for (int e = 0; e < 4; ++e) {
                m[e] = m[e] + (acc[i][e] - m[e]) * 0.5f;
                const float s = (m[e] - 1.0f > 0.0f) ? 1.0f : 0.0f;
                mc[e] |= (s > 0.0f) ? (1u << t) : 0u;
                m[e] *= (1.0f - s);
            }
        }
    }

    uint4 mv;
    mv.x = mc[0]; mv.y = mc[1]; mv.z = mc[2]; mv.w = mc[3];
    *reinterpret_cast<uint4*>(&gmsk[base + e0]) = mv;
}

// ================= Kernel B: GEMM2 via bf16 MFMA ===========================
// 2 tokens/block, 256 thr (4 waves: token x t-half). A-frag per-ks from
// global x + LDS mask (r7/r10-verified). C staged in LDS -> coalesced writes.
#define CP 132   // padded C row pitch (floats)

template<bool UW>
__global__ __launch_bounds__(256, 2) void lif_phaseB(
    const float* __restrict__ x,      // [T,B,N,D]
    const float* __restrict__ Wr,     // [D,D]
    const float* __restrict__ br,     // [D]
    const unsigned short* __restrict__ Wt,  // [D,D] bf16 transposed (if UW)
    const unsigned* __restrict__ gmsk,      // [B*N, D]
    float* __restrict__ out)          // [T,B,N,D]
{
    __shared__ __align__(16) unsigned ms[2 * DD];      // 4 KB
    __shared__ __align__(16) float cs[2 * TT * CP];    // 33 KB C stage

    const int tid = threadIdx.x;          // 0..255
    const size_t st = (size_t)BB * NN * DD;

    // stage both tokens' masks
    {
        const uint4 v = *reinterpret_cast<const uint4*>(
            &gmsk[(size_t)blockIdx.x * 2 * DD + tid * 4]);
        *reinterpret_cast<uint4*>(&ms[tid * 4]) = v;
    }
    __syncthreads();

    const int wv   = tid >> 6;            // 0..3
    const int lane = tid & 63;
    const int qB   = wv >> 1;             // token within block
    const int hB   = wv & 1;              // t-half
    const int lcol = lane & 15;
    const int lkg  = lane >> 4;           // 0..3
    const int tA   = hB * 16 + lcol;      // A-frag row (t) this lane supplies
    const size_t baseB = (size_t)(blockIdx.x * 2 + qB) * DD;
    const unsigned* mq = &ms[qB * DD];
    const float* xrow = &x[(size_t)tA * st + baseB];

    #pragma unroll 1
    for (int pass = 0; pass < 4; ++pass) {
        const int colb = pass * 128;
        f32x4 acc[8];
        #pragma unroll
        for (int nt = 0; nt < 8; ++nt) {
            const float b = br[colb + nt * 16 + lcol];
            acc[nt] = (f32x4){b, b, b, b};
        }

        #pragma unroll
        for (int ks = 0; ks < 16; ++ks) {
            const int kb = ks * 32 + lkg * 8;
            const float4 x0 = *reinterpret_cast<const float4*>(&xrow[kb]);
            const float4 x1 = *reinterpret_cast<const float4*>(&xrow[kb + 4]);
            const uint4 m0 = *reinterpret_cast<const uint4*>(&mq[kb]);
            const uint4 m1 = *reinterpret_cast<const uint4*>(&mq[kb + 4]);
            short8 a;
            a[0] = (short)f2bf(((m0.x >> tA) & 1u) ? 0.0f : x0.x);
            a[1] = (short)f2bf(((m0.y >> tA) & 1u) ? 0.0f : x0.y);
            a[2] = (short)f2bf(((m0.z >> tA) & 1u) ? 0.0f : x0.z);
            a[3] = (short)f2bf(((m0.w >> tA) & 1u) ? 0.0f : x0.w);
            a[4] = (short)f2bf(((m1.x >> tA) & 1u) ? 0.0f : x1.x);
            a[5] = (short)f2bf(((m1.y >> tA) & 1u) ? 0.0f : x1.y);
            a[6] = (short)f2bf(((m1.z >> tA) & 1u) ? 0.0f : x1.z);
            a[7] = (short)f2bf(((m1.w >> tA) & 1u) ? 0.0f : x1.w);

            #pragma unroll
            for (int nt = 0; nt < 8; ++nt) {
                const int col = colb + nt * 16 + lcol;
                short8 bf;
                if (UW) {
                    bf = *reinterpret_cast<const short8*>(&Wt[(size_t)col * DD + kb]);
                } else {
                    #pragma unroll
                    for (int j = 0; j < 8; ++j)
                        bf[j] = (short)f2bf(Wr[(size_t)(kb + j) * DD + col]);
                }
                acc[nt] = __builtin_amdgcn_mfma_f32_16x16x32_bf16(a, bf, acc[nt], 0, 0, 0);
            }
        }

        // stage C fragments -> LDS (C/D layout: col=lane&15, row=(lane>>4)*4+r)
        #pragma unroll
        for (int nt = 0; nt < 8; ++nt) {
            #pragma unroll
            for (int r = 0; r < 4; ++r) {
                const int t = hB * 16 + lkg * 4 + r;
                cs[(qB * TT + t) * CP + nt * 16 + lcol] = acc[nt][r];
            }
        }
        __syncthreads();

        // coalesced write: 64 segments of 128 floats (512B contiguous rows)
        #pragma unroll
        for (int k = 0; k < 8; ++k) {
            const int flat = k * 256 + tid;     // 0..2047 float4 slots
            const int seg  = flat >> 5;         // 0..63 -> (q,t)
            const int wi   = flat & 31;         // float4 within row
            const int q    = seg >> 5;
            const int t    = seg & 31;
            float4 v = *reinterpret_cast<const float4*>(&cs[(q * TT + t) * CP + wi * 4]);
            *reinterpret_cast<float4*>(
                &out[(size_t)t * st + (size_t)(blockIdx.x * 2 + q) * DD + colb + wi * 4]) = v;
        }
        __syncthreads();   // copy done before next pass overwrites cs
    }
}

// ================= Fallback: r10 fused kernel (ws too small) ===============
template<bool UW>
__global__ __launch_bounds__(256, 2) void lif_decoder_v10(
    const float* __restrict__ x, const float* __restrict__ tr_mx,
    const float* __restrict__ Wl, const float* __restrict__ bl,
    const float* __restrict__ Wr, const float* __restrict__ br,
    const unsigned short* __restrict__ Wt, float* __restrict__ out)
{
    __shared__ __align__(16) float xs[2 * CH * DD];
    __shared__ __align__(16) unsigned msk[2 * DD];

    const int tid = threadIdx.x;
    const int tg  = tid >> 7;
    const int tl  = tid & 127;
    const int e0  = tl * 4;
    const int tok = blockIdx.x * 2 + tg;
    const size_t base = (size_t)tok * DD;
    const size_t st   = (size_t)BB * NN * DD;

    {
        float acc[CH][4];
        float4 m4 = *reinterpret_cast<const float4*>(&tr_mx[base + e0]);
        float m[4] = {m4.x, m4.y, m4.z, m4.w};
        unsigned mc[4] = {0u, 0u, 0u, 0u};
        const float4 blv = *reinterpret_cast<const float4*>(&bl[e0]);
        const float blr[4] = {blv.x, blv.y, blv.z, blv.w};

        #pragma unroll 1
        for (int tgc = 0; tgc < 4; ++tgc) {
            #pragma unroll
            for (int r = 0; r < 8; ++r) {
                const int flat = r * 256 + tid;
                const int q    = flat >> 10;
                const int rem  = flat & 1023;
                const int trow = rem >> 7;
                const int c4   = rem & 127;
                const float4 v = *reinterpret_cast<const float4*>(
                    &x[(size_t)(tgc * CH + trow) * st
                       + (size_t)(blockIdx.x * 2 + q) * DD + c4 * 4]);
                *reinterpret_cast<float4*>(&xs[(q * CH + trow) * DD + c4 * 4]) = v;
            }
            __syncthreads();

            #pragma unroll
            for (int i = 0; i < CH; ++i)
                #pragma unroll
                for (int e = 0; e < 4; ++e) acc[i][e] = blr[e];

            const float* xsl = &xs[tg * CH * DD];
            #pragma unroll 2
            for (int d = 0; d < DD; d += 4) {
                const float4 w0 = *reinterpret_cast<const float4*>(&Wl[(size_t)(d + 0) * DD + e0]);
                const float4 w1 = *reinterpret_cast<const float4*>(&Wl[(size_t)(d + 1) * DD + e0]);
                const float4 w2 = *reinterpret_cast<const float4*>(&Wl[(size_t)(d + 2) * DD + e0]);
                const float4 w3 = *reinterpret_cast<const float4*>(&Wl[(size_t)(d + 3) * DD + e0]);
                #pragma unroll
                for (int i = 0; i < CH; ++i) {
                    const float4 xv = *reinterpret_cast<const float4*>(&xsl[i * DD + d]);
                    acc[i][0] = fmaf(xv.x, w0.x, acc[i][0]);
                    acc[i][1] = fmaf(xv.x, w0.y, acc[i][1]);
                    acc[i][2] = fmaf(xv.x, w0.z, acc[i][2]);
                    acc[i][3] = fmaf(xv.x, w0.w, acc[i][3]);
                    acc[i][0] = fmaf(xv.y, w1.x, acc[i][0]);
                    acc[i][1] = fmaf(xv.y, w1.y, acc[i][1]);
                    acc[i][2] = fmaf(xv.y, w1.z, acc[i][2]);
                    acc[i][3] = fmaf(xv.y, w1.w, acc[i][3]);
                    acc[i][0] = fmaf(xv.z, w2.x, acc[i][0]);
                    acc[i][1] = fmaf(xv.z, w2.y, acc[i][1]);
                    acc[i][2] = fmaf(xv.z, w2.z, acc[i][2]);
                    acc[i][3] = fmaf(xv.z, w2.w, acc[i][3]);
                    acc[i][0] = fmaf(xv.w, w3.x, acc[i][0]);
                    acc[i][1] = fmaf(xv.w, w3.y, acc[i][1]);
                    acc[i][2] = fmaf(xv.w, w3.z, acc[i][2]);
                    acc[i][3] = fmaf(xv.w, w3.w, acc[i][3]);
                }
            }
            __syncthreads();

            #pragma unroll
            for (int i = 0; i < CH; ++i) {
                const int t = tgc * CH + i;
                #pragma unroll
                for (int e = 0; e < 4; ++e) {
                    m[e] = m[e] + (acc[i][e] - m[e]) * 0.5f;
                    const float s = (m[e] - 1.0f > 0.0f) ? 1.0f : 0.0f;
                    mc[e] |= (s > 0.0f) ? (1u << t) : 0u;
                    m[e] *= (1.0f - s);
                }
            }
        }
        #pragma unroll
        for (int e = 0; e < 4; ++e) msk[tg * DD + e0 + e] = mc[e];
    }
    __syncthreads();

    {
        const int wv   = tid >> 6;
        const int lane = tid & 63;
        const int qB   = wv >> 1;
        const int hB   = wv & 1;
        const int lcol = lane & 15;
        const int lkg  = lane >> 4;
        const int tA   = hB * 16 + lcol;
        const size_t baseB = (size_t)(blockIdx.x * 2 + qB) * DD;
        const unsigned* mq = &msk[qB * DD];
        const float* xrow = &x[(size_t)tA * st + baseB];

        #pragma unroll 1
        for (int pass = 0; pass < 4; ++pass) {
            const int colb = pass * 128;
            f32x4 acc[8];
            #pragma unroll
            for (int nt = 0; nt < 8; ++nt) {
                const float b = br[colb + nt * 16 + lcol];
                acc[nt] = (f32x4){b, b, b, b};
            }
            #pragma unroll
            for (int ks = 0; ks < 16; ++ks) {
                const int kb = ks * 32 + lkg * 8;
                const float4 x0 = *reinterpret_cast<const float4*>(&xrow[kb]);
                const float4 x1 = *reinterpret_cast<const float4*>(&xrow[kb + 4]);
                const uint4 m0 = *reinterpret_cast<const uint4*>(&mq[kb]);
                const uint4 m1 = *reinterpret_cast<const uint4*>(&mq[kb + 4]);
                short8 a;
                a[0] = (short)f2bf(((m0.x >> tA) & 1u) ? 0.0f : x0.x);
                a[1] = (short)f2bf(((m0.y >> tA) & 1u) ? 0.0f : x0.y);
                a[2] = (short)f2bf(((m0.z >> tA) & 1u) ? 0.0f : x0.z);
                a[3] = (short)f2bf(((m0.w >> tA) & 1u) ? 0.0f : x0.w);
                a[4] = (short)f2bf(((m1.x >> tA) & 1u) ? 0.0f : x1.x);
                a[5] = (short)f2bf(((m1.y >> tA) & 1u) ? 0.0f : x1.y);
                a[6] = (short)f2bf(((m1.z >> tA) & 1u) ? 0.0f : x1.z);
                a[7] = (short)f2bf(((m1.w >> tA) & 1u) ? 0.0f : x1.w);
                #pragma unroll
                for (int nt = 0; nt < 8; ++nt) {
                    const int col = colb + nt * 16 + lcol;
                    short8 bf;
                    if (UW) {
                        bf = *reinterpret_cast<const short8*>(&Wt[(size_t)col * DD + kb]);
                    } else {
                        #pragma unroll
                        for (int j = 0; j < 8; ++j)
                            bf[j] = (short)f2bf(Wr[(size_t)(kb + j) * DD + col]);
                    }
                    acc[nt] = __builtin_amdgcn_mfma_f32_16x16x32_bf16(a, bf, acc[nt], 0, 0, 0);
                }
            }
            #pragma unroll
            for (int nt = 0; nt < 8; ++nt) {
                const int col = colb + nt * 16 + lcol;
                #pragma unroll
                for (int r = 0; r < 4; ++r) {
                    const int t = hB * 16 + lkg * 4 + r;
                    out[(size_t)t * st + baseB + col] = acc[nt][r];
                }
            }
        }
    }
}

extern "C" void kernel_launch(void* const* d_in, const int* in_sizes, int n_in,
                              void* d_out, int out_size, void* d_ws, size_t ws_size,
                              hipStream_t stream) {
    const float* x     = (const float*)d_in[0];
    const float* tr_mx = (const float*)d_in[1];
    const float* Wl    = (const float*)d_in[2];
    const float* bl    = (const float*)d_in[3];
    const float* Wr    = (const float*)d_in[4];
    const float* br    = (const float*)d_in[5];
    float* out = (float*)d_out;

    const size_t msk_bytes = (size_t)BB * NN * DD * 4;   // 4 MB
    const size_t wt_bytes  = (size_t)DD * DD * 2;        // 512 KB

    if (ws_size >= msk_bytes + wt_bytes) {
        unsigned* gmsk = (unsigned*)d_ws;
        unsigned short* Wt = (unsigned short*)((char*)d_ws + msk_bytes);
        cast_transpose_wr<<<dim3(1024), dim3(256), 0, stream>>>(Wr, Wt);
        lif_phaseA<<<dim3(BB * NN), dim3(128), 0, stream>>>(x, tr_mx, Wl, bl, gmsk);
        lif_phaseB<true><<<dim3(BB * NN / 2), dim3(256), 0, stream>>>(x, Wr, br, Wt, gmsk, out);
    } else if (ws_size >= wt_bytes) {
        unsigned short* Wt = (unsigned short*)d_ws;
        cast_transpose_wr<<<dim3(1024), dim3(256), 0, stream>>>(Wr, Wt);
        lif_decoder_v10<true><<<dim3(BB * NN / 2), dim3(256), 0, stream>>>(x, tr_mx, Wl, bl, Wr, br, Wt, out);
    } else {
        lif_decoder_v10<false><<<dim3(BB * NN / 2), dim3(256), 0, stream>>>(x, tr_mx, Wl, bl, Wr, br, nullptr, out);
    }
}

// Round 12
// 836.121 us; speedup vs baseline: 1.0583x; 1.0583x over previous
//
#include <hip/hip_runtime.h>
#include <hip/hip_bf16.h>

// Decoder_21208548508049 — round 12.
// Empirical codegen law (9 rounds): VGPR = 256 / launch_bounds_arg2.
// Phase A v2: 2 e/thread, 256 thr/token -> 8192 waves (32/CU); live ~55 regs
//   fits the 64-VGPR budget (arg2=4). Full-d ascending fmaf chain + LIF
//   verbatim -> spikes bit-identical (r1/4/5/6/10/11 proven).
// Phase B v2: r10's direct-store MFMA GEMM2 (A-frag per-ks from x + mask),
//   ks-loop unroll 1 (kill the 128-deep unroll spill), mask via LDS.
//
// T=32,B=8,N=256,D=512.

#define TT 32
#define CH 8
#define BB 8
#define NN 256
#define DD 512

typedef __attribute__((ext_vector_type(8))) short short8;
typedef __attribute__((ext_vector_type(4))) float f32x4;

__device__ __forceinline__ unsigned short f2bf(float f) {
    __hip_bfloat16 h = __float2bfloat16(f);
    return *reinterpret_cast<unsigned short*>(&h);
}

// ---- pre-kernel: Wt[p][d] = bf16(Wr[d][p]) ----
__global__ void cast_transpose_wr(const float* __restrict__ Wr,
                                  unsigned short* __restrict__ Wt) {
    int idx = blockIdx.x * 256 + threadIdx.x;      // 0..262143
    int d = idx >> 9;
    int p = idx & 511;
    Wt[p * DD + d] = f2bf(Wr[idx]);
}

// ================= Kernel A v2: GEMM1 (exact f32) + LIF -> global bitmask ===
// 1 token/block, 256 threads, e0 = tid*2 (2 cols/thread). 8192 waves total.
__global__ __launch_bounds__(256, 4) void lif_phaseA2(
    const float* __restrict__ x,      // [T,B,N,D]
    const float* __restrict__ tr_mx,  // [B,N,D]
    const float* __restrict__ Wl,     // [D,D]
    const float* __restrict__ bl,     // [D]
    unsigned* __restrict__ gmsk)      // [B*N, D] spike bits: (gmsk[tok*D+d]>>t)&1
{
    __shared__ __align__(16) float xs[CH * DD];    // 16 KB: one t-chunk, full d

    const int tid = threadIdx.x;          // 0..255
    const int tok = blockIdx.x;           // 0..2047
    const int e0  = tid * 2;
    const size_t base = (size_t)tok * DD;
    const size_t st   = (size_t)BB * NN * DD;

    float acc[CH][2];
    const float2 m2 = *reinterpret_cast<const float2*>(&tr_mx[base + e0]);
    float m[2] = {m2.x, m2.y};
    unsigned mc[2] = {0u, 0u};

    const float2 blv = *reinterpret_cast<const float2*>(&bl[e0]);
    const float blr[2] = {blv.x, blv.y};

    #pragma unroll 1
    for (int tg = 0; tg < 4; ++tg) {
        // stage x[tg*8 .. +7][0..511]: 4 float4/thread, coalesced
        #pragma unroll
        for (int r = 0; r < 4; ++r) {
            const int flat = r * 256 + tid;        // 0..1023
            const int row  = flat >> 7;            // 0..7
            const int c4   = flat & 127;
            const float4 v = *reinterpret_cast<const float4*>(
                &x[(size_t)(tg * CH + row) * st + base + c4 * 4]);
            *reinterpret_cast<float4*>(&xs[row * DD + c4 * 4]) = v;
        }
        __syncthreads();

        #pragma unroll
        for (int i = 0; i < CH; ++i) {
            acc[i][0] = blr[0];
            acc[i][1] = blr[1];
        }

        #pragma unroll 2
        for (int d = 0; d < DD; d += 4) {
            const float2 w0 = *reinterpret_cast<const float2*>(&Wl[(size_t)(d + 0) * DD + e0]);
            const float2 w1 = *reinterpret_cast<const float2*>(&Wl[(size_t)(d + 1) * DD + e0]);
            const float2 w2 = *reinterpret_cast<const float2*>(&Wl[(size_t)(d + 2) * DD + e0]);
            const float2 w3 = *reinterpret_cast<const float2*>(&Wl[(size_t)(d + 3) * DD + e0]);
            #pragma unroll
            for (int i = 0; i < CH; ++i) {
                const float4 xv = *reinterpret_cast<const float4*>(&xs[i * DD + d]);
                // d-ascending fmaf chain per (t,e): identical to all prior passes
                acc[i][0] = fmaf(xv.x, w0.x, acc[i][0]);
                acc[i][1] = fmaf(xv.x, w0.y, acc[i][1]);
                acc[i][0] = fmaf(xv.y, w1.x, acc[i][0]);
                acc[i][1] = fmaf(xv.y, w1.y, acc[i][1]);
                acc[i][0] = fmaf(xv.z, w2.x, acc[i][0]);
                acc[i][1] = fmaf(xv.z, w2.y, acc[i][1]);
                acc[i][0] = fmaf(xv.w, w3.x, acc[i][0]);
                acc[i][1] = fmaf(xv.w, w3.y, acc[i][1]);
            }
        }
        __syncthreads();   // xs reads done before next chunk overwrites

        // LIF for this chunk (identical arithmetic to all prior passes)
        #pragma unroll
        for (int i = 0; i < CH; ++i) {
            const int t = tg * CH + i;
            #pragma unroll
            for (int e = 0; e < 2; ++e) {
                m[e] = m[e] + (acc[i][e] - m[e]) * 0.5f;
                const float s = (m[e] - 1.0f > 0.0f) ? 1.0f : 0.0f;
                mc[e] |= (s > 0.0f) ? (1u << t) : 0u;
                m[e] *= (1.0f - s);
            }
        }
    }

    uint2 mv;
    mv.x = mc[0];
    mv.y = mc[1];
    *reinterpret_cast<uint2*>(&gmsk[base + e0]) = mv;
}

// ================= Kernel B v2: GEMM2 via bf16 MFMA (direct stores) ========
// 2 tokens/block, 256 thr (4 waves: token x t-half). A-frag per-ks from
// global x + LDS mask (r7/r10-verified). ks-loop unroll 1 -> no spill.
template<bool UW>
__global__ __launch_bounds__(256, 2) void lif_phaseB2(
    const float* __restrict__ x,      // [T,B,N,D]
    const float* __restrict__ Wr,     // [D,D]
    const float* __restrict__ br,     // [D]
    const unsigned short* __restrict__ Wt,  // [D,D] bf16 transposed (if UW)
    const unsigned* __restrict__ gmsk,      // [B*N, D]
    float* __restrict__ out)          // [T,B,N,D]
{
    __shared__ __align__(16) unsigned ms[2 * DD];      // 4 KB

    const int tid = threadIdx.x;          // 0..255
    const size_t st = (size_t)BB * NN * DD;

    // stage both tokens' masks
    {
        const uint4 v = *reinterpret_cast<const uint4*>(
            &gmsk[(size_t)blockIdx.x * 2 * DD + tid * 4]);
        *reinterpret_cast<uint4*>(&ms[tid * 4]) = v;
    }
    __syncthreads();

    const int wv   = tid >> 6;            // 0..3
    const int lane = tid & 63;
    const int qB   = wv >> 1;             // token within block
    const int hB   = wv & 1;              // t-half
    const int lcol = lane & 15;
    const int lkg  = lane >> 4;           // 0..3
    const int tA   = hB * 16 + lcol;      // A-frag row (t) this lane supplies
    const size_t baseB = (size_t)(blockIdx.x * 2 + qB) * DD;
    const unsigned* mq = &ms[qB * DD];
    const float* xrow = &x[(size_t)tA * st + baseB];

    #pragma unroll 1
    for (int pass = 0; pass < 4; ++pass) {
        const int colb = pass * 128;
        f32x4 acc[8];
        #pragma unroll
        for (int nt = 0; nt < 8; ++nt) {
            const float b = br[colb + nt * 16 + lcol];
            acc[nt] = (f32x4){b, b, b, b};
        }

        #pragma unroll 1
        for (int ks = 0; ks < 16; ++ks) {
            const int kb = ks * 32 + lkg * 8;
            const float4 x0 = *reinterpret_cast<const float4*>(&xrow[kb]);
            const float4 x1 = *reinterpret_cast<const float4*>(&xrow[kb + 4]);
            const uint4 m0 = *reinterpret_cast<const uint4*>(&mq[kb]);
            const uint4 m1 = *reinterpret_cast<const uint4*>(&mq[kb + 4]);
            short8 a;
            a[0] = (short)f2bf(((m0.x >> tA) & 1u) ? 0.0f : x0.x);
            a[1] = (short)f2bf(((m0.y >> tA) & 1u) ? 0.0f : x0.y);
            a[2] = (short)f2bf(((m0.z >> tA) & 1u) ? 0.0f : x0.z);
            a[3] = (short)f2bf(((m0.w >> tA) & 1u) ? 0.0f : x0.w);
            a[4] = (short)f2bf(((m1.x >> tA) & 1u) ? 0.0f : x1.x);
            a[5] = (short)f2bf(((m1.y >> tA) & 1u) ? 0.0f : x1.y);
            a[6] = (short)f2bf(((m1.z >> tA) & 1u) ? 0.0f : x1.z);
            a[7] = (short)f2bf(((m1.w >> tA) & 1u) ? 0.0f : x1.w);

            #pragma unroll
            for (int nt = 0; nt < 8; ++nt) {
                const int col = colb + nt * 16 + lcol;
                short8 bf;
                if (UW) {
                    bf = *reinterpret_cast<const short8*>(&Wt[(size_t)col * DD + kb]);
                } else {
                    #pragma unroll
                    for (int j = 0; j < 8; ++j)
                        bf[j] = (short)f2bf(Wr[(size_t)(kb + j) * DD + col]);
                }
                acc[nt] = __builtin_amdgcn_mfma_f32_16x16x32_bf16(a, bf, acc[nt], 0, 0, 0);
            }
        }

        // epilogue: C/D layout col=lane&15, row=(lane>>4)*4+r (verified r7/r10)
        #pragma unroll
        for (int nt = 0; nt < 8; ++nt) {
            const int col = colb + nt * 16 + lcol;
            #pragma unroll
            for (int r = 0; r < 4; ++r) {
                const int t = hB * 16 + lkg * 4 + r;
                out[(size_t)t * st + baseB + col] = acc[nt][r];
            }
        }
    }
}

// ================= Fallback: r10 fused kernel (ws too small) ===============
template<bool UW>
__global__ __launch_bounds__(256, 2) void lif_decoder_v10(
    const float* __restrict__ x, const float* __restrict__ tr_mx,
    const float* __restrict__ Wl, const float* __restrict__ bl,
    const float* __restrict__ Wr, const float* __restrict__ br,
    const unsigned short* __restrict__ Wt, float* __restrict__ out)
{
    __shared__ __align__(16) float xs[2 * CH * DD];
    __shared__ __align__(16) unsigned msk[2 * DD];

    const int tid = threadIdx.x;
    const int tg  = tid >> 7;
    const int tl  = tid & 127;
    const int e0  = tl * 4;
    const int tok = blockIdx.x * 2 + tg;
    const size_t base = (size_t)tok * DD;
    const size_t st   = (size_t)BB * NN * DD;

    {
        float acc[CH][4];
        float4 m4 = *reinterpret_cast<const float4*>(&tr_mx[base + e0]);
        float m[4] = {m4.x, m4.y, m4.z, m4.w};
        unsigned mc[4] = {0u, 0u, 0u, 0u};
        const float4 blv = *reinterpret_cast<const float4*>(&bl[e0]);
        const float blr[4] = {blv.x, blv.y, blv.z, blv.w};

        #pragma unroll 1
        for (int tgc = 0; tgc < 4; ++tgc) {
            #pragma unroll
            for (int r = 0; r < 8; ++r) {
                const int flat = r * 256 + tid;
                const int q    = flat >> 10;
                const int rem  = flat & 1023;
                const int trow = rem >> 7;
                const int c4   = rem & 127;
                const float4 v = *reinterpret_cast<const float4*>(
                    &x[(size_t)(tgc * CH + trow) * st
                       + (size_t)(blockIdx.x * 2 + q) * DD + c4 * 4]);
                *reinterpret_cast<float4*>(&xs[(q * CH + trow) * DD + c4 * 4]) = v;
            }
            __syncthreads();

            #pragma unroll
            for (int i = 0; i < CH; ++i)
                #pragma unroll
                for (int e = 0; e < 4; ++e) acc[i][e] = blr[e];

            const float* xsl = &xs[tg * CH * DD];
            #pragma unroll 2
            for (int d = 0; d < DD; d += 4) {
                const float4 w0 = *reinterpret_cast<const float4*>(&Wl[(size_t)(d + 0) * DD + e0]);
                const float4 w1 = *reinterpret_cast<const float4*>(&Wl[(size_t)(d + 1) * DD + e0]);
                const float4 w2 = *reinterpret_cast<const float4*>(&Wl[(size_t)(d + 2) * DD + e0]);
                const float4 w3 = *reinterpret_cast<const float4*>(&Wl[(size_t)(d + 3) * DD + e0]);
                #pragma unroll
                for (int i = 0; i < CH; ++i) {
                    const float4 xv = *reinterpret_cast<const float4*>(&xsl[i * DD + d]);
                    acc[i][0] = fmaf(xv.x, w0.x, acc[i][0]);
                    acc[i][1] = fmaf(xv.x, w0.y, acc[i][1]);
                    acc[i][2] = fmaf(xv.x, w0.z, acc[i][2]);
                    acc[i][3] = fmaf(xv.x, w0.w, acc[i][3]);
                    acc[i][0] = fmaf(xv.y, w1.x, acc[i][0]);
                    acc[i][1] = fmaf(xv.y, w1.y, acc[i][1]);
                    acc[i][2] = fmaf(xv.y, w1.z, acc[i][2]);
                    acc[i][3] = fmaf(xv.y, w1.w, acc[i][3]);
                    acc[i][0] = fmaf(xv.z, w2.x, acc[i][0]);
                    acc[i][1] = fmaf(xv.z, w2.y, acc[i][1]);
                    acc[i][2] = fmaf(xv.z, w2.z, acc[i][2]);
                    acc[i][3] = fmaf(xv.z, w2.w, acc[i][3]);
                    acc[i][0] = fmaf(xv.w, w3.x, acc[i][0]);
                    acc[i][1] = fmaf(xv.w, w3.y, acc[i][1]);
                    acc[i][2] = fmaf(xv.w, w3.z, acc[i][2]);
                    acc[i][3] = fmaf(xv.w, w3.w, acc[i][3]);
                }
            }
            __syncthreads();

            #pragma unroll
            for (int i = 0; i < CH; ++i) {
                const int t = tgc * CH + i;
                #pragma unroll
                for (int e = 0; e < 4; ++e) {
                    m[e] = m[e] + (acc[i][e] - m[e]) * 0.5f;
                    const float s = (m[e] - 1.0f > 0.0f) ? 1.0f : 0.0f;
                    mc[e] |= (s > 0.0f) ? (1u << t) : 0u;
                    m[e] *= (1.0f - s);
                }
            }
        }
        #pragma unroll
        for (int e = 0; e < 4; ++e) msk[tg * DD + e0 + e] = mc[e];
    }
    __syncthreads();

    {
        const int wv   = tid >> 6;
        const int lane = tid & 63;
        const int qB   = wv >> 1;
        const int hB   = wv & 1;
        const int lcol = lane & 15;
        const int lkg  = lane >> 4;
        const int tA   = hB * 16 + lcol;
        const size_t baseB = (size_t)(blockIdx.x * 2 + qB) * DD;
        const unsigned* mq = &msk[qB * DD];
        const float* xrow = &x[(size_t)tA * st + baseB];

        #pragma unroll 1
        for (int pass = 0; pass < 4; ++pass) {
            const int colb = pass * 128;
            f32x4 acc[8];
            #pragma unroll
            for (int nt = 0; nt < 8; ++nt) {
                const float b = br[colb + nt * 16 + lcol];
                acc[nt] = (f32x4){b, b, b, b};
            }
            #pragma unroll 1
            for (int ks = 0; ks < 16; ++ks) {
                const int kb = ks * 32 + lkg * 8;
                const float4 x0 = *reinterpret_cast<const float4*>(&xrow[kb]);
                const float4 x1 = *reinterpret_cast<const float4*>(&xrow[kb + 4]);
                const uint4 m0 = *reinterpret_cast<const uint4*>(&mq[kb]);
                const uint4 m1 = *reinterpret_cast<const uint4*>(&mq[kb + 4]);
                short8 a;
                a[0] = (short)f2bf(((m0.x >> tA) & 1u) ? 0.0f : x0.x);
                a[1] = (short)f2bf(((m0.y >> tA) & 1u) ? 0.0f : x0.y);
                a[2] = (short)f2bf(((m0.z >> tA) & 1u) ? 0.0f : x0.z);
                a[3] = (short)f2bf(((m0.w >> tA) & 1u) ? 0.0f : x0.w);
                a[4] = (short)f2bf(((m1.x >> tA) & 1u) ? 0.0f : x1.x);
                a[5] = (short)f2bf(((m1.y >> tA) & 1u) ? 0.0f : x1.y);
                a[6] = (short)f2bf(((m1.z >> tA) & 1u) ? 0.0f : x1.z);
                a[7] = (short)f2bf(((m1.w >> tA) & 1u) ? 0.0f : x1.w);
                #pragma unroll
                for (int nt = 0; nt < 8; ++nt) {
                    const int col = colb + nt * 16 + lcol;
                    short8 bf;
                    if (UW) {
                        bf = *reinterpret_cast<const short8*>(&Wt[(size_t)col * DD + kb]);
                    } else {
                        #pragma unroll
                        for (int j = 0; j < 8; ++j)
                            bf[j] = (short)f2bf(Wr[(size_t)(kb + j) * DD + col]);
                    }
                    acc[nt] = __builtin_amdgcn_mfma_f32_16x16x32_bf16(a, bf, acc[nt], 0, 0, 0);
                }
            }
            #pragma unroll
            for (int nt = 0; nt < 8; ++nt) {
                const int col = colb + nt * 16 + lcol;
                #pragma unroll
                for (int r = 0; r < 4; ++r) {
                    const int t = hB * 16 + lkg * 4 + r;
                    out[(size_t)t * st + baseB + col] = acc[nt][r];
                }
            }
        }
    }
}

extern "C" void kernel_launch(void* const* d_in, const int* in_sizes, int n_in,
                              void* d_out, int out_size, void* d_ws, size_t ws_size,
                              hipStream_t stream) {
    const float* x     = (const float*)d_in[0];
    const float* tr_mx = (const float*)d_in[1];
    const float* Wl    = (const float*)d_in[2];
    const float* bl    = (const float*)d_in[3];
    const float* Wr    = (const float*)d_in[4];
    const float* br    = (const float*)d_in[5];
    float* out = (float*)d_out;

    const size_t msk_bytes = (size_t)BB * NN * DD * 4;   // 4 MB
    const size_t wt_bytes  = (size_t)DD * DD * 2;        // 512 KB

    if (ws_size >= msk_bytes + wt_bytes) {
        unsigned* gmsk = (unsigned*)d_ws;
        unsigned short* Wt = (unsigned short*)((char*)d_ws + msk_bytes);
        cast_transpose_wr<<<dim3(1024), dim3(256), 0, stream>>>(Wr, Wt);
        lif_phaseA2<<<dim3(BB * NN), dim3(256), 0, stream>>>(x, tr_mx, Wl, bl, gmsk);
        lif_phaseB2<true><<<dim3(BB * NN / 2), dim3(256), 0, stream>>>(x, Wr, br, Wt, gmsk, out);
    } else if (ws_size >= wt_bytes) {
        unsigned short* Wt = (unsigned short*)d_ws;
        cast_transpose_wr<<<dim3(1024), dim3(256), 0, stream>>>(Wr, Wt);
        lif_decoder_v10<true><<<dim3(BB * NN / 2), dim3(256), 0, stream>>>(x, tr_mx, Wl, bl, Wr, br, Wt, out);
    } else {
        lif_decoder_v10<false><<<dim3(BB * NN / 2), dim3(256), 0, stream>>>(x, tr_mx, Wl, bl, Wr, br, nullptr, out);
    }
}

// Round 13
// 763.756 us; speedup vs baseline: 1.1585x; 1.0947x over previous
//
#include <hip/hip_runtime.h>
#include <hip/hip_bf16.h>

// Decoder_21208548508049 — round 13.
// r12 lessons: (1) 4e/thread is phase-A's sweet spot (2e halves FMA/mem ratio:
//   488 -> 600us); (2) phase B's cost is the per-ks x-load->mask->cvt chain.
// Fix: phase A materializes g = (spike ? 0 : x) as bf16 into workspace (67MB);
// phase B becomes a pure bf16 GEMM (contiguous A-frag loads, no masks/cvt).
// Numerics: f2bf(select(x)) identical to r7-r12 -> absmax 0.03125; phase-A
// fmaf chain is the r6-proven full-d version -> spikes bit-identical.
//
// T=32,B=8,N=256,D=512.

#define TT 32
#define CH 8
#define BB 8
#define NN 256
#define DD 512

typedef __attribute__((ext_vector_type(8))) short short8;
typedef __attribute__((ext_vector_type(4))) float f32x4;

__device__ __forceinline__ unsigned short f2bf(float f) {
    __hip_bfloat16 h = __float2bfloat16(f);
    return *reinterpret_cast<unsigned short*>(&h);
}

// ---- pre-kernel: Wt[p][d] = bf16(Wr[d][p]) ----
__global__ void cast_transpose_wr(const float* __restrict__ Wr,
                                  unsigned short* __restrict__ Wt) {
    int idx = blockIdx.x * 256 + threadIdx.x;      // 0..262143
    int d = idx >> 9;
    int p = idx & 511;
    Wt[p * DD + d] = f2bf(Wr[idx]);
}

// ========== Tier-1 Phase A: GEMM1 (exact f32) + LIF -> g (bf16) ==========
// 1 token/block, 128 thr, e0 = tid*4 (r6-proven full-d chain, 64 VGPR).
__global__ __launch_bounds__(128, 4) void lif_phaseA_g(
    const float* __restrict__ x,      // [T,B,N,D]
    const float* __restrict__ tr_mx,  // [B,N,D]
    const float* __restrict__ Wl,     // [D,D]
    const float* __restrict__ bl,     // [D]
    unsigned short* __restrict__ gws) // [B*N*T, D] bf16: g[tok*32+t][e]
{
    __shared__ __align__(16) float xs[CH * DD];    // 16 KB

    const int tid = threadIdx.x;          // 0..127
    const int tok = blockIdx.x;           // 0..2047
    const int e0  = tid * 4;
    const size_t base = (size_t)tok * DD;
    const size_t st   = (size_t)BB * NN * DD;

    float acc[CH][4];
    float4 m4 = *reinterpret_cast<const float4*>(&tr_mx[base + e0]);
    float m[4] = {m4.x, m4.y, m4.z, m4.w};

    const float4 blv = *reinterpret_cast<const float4*>(&bl[e0]);
    const float blr[4] = {blv.x, blv.y, blv.z, blv.w};

    #pragma unroll 1
    for (int tg = 0; tg < 4; ++tg) {
        // stage x[tg*8 .. +7][0..511]: 8 float4/thread, coalesced (r6 pattern)
        #pragma unroll
        for (int r = 0; r < 8; ++r) {
            const int flat = r * 128 + tid;        // 0..1023
            const int row  = flat >> 7;            // 0..7
            const int c4   = flat & 127;
            const float4 v = *reinterpret_cast<const float4*>(
                &x[(size_t)(tg * CH + row) * st + base + c4 * 4]);
            *reinterpret_cast<float4*>(&xs[row * DD + c4 * 4]) = v;
        }
        __syncthreads();

        #pragma unroll
        for (int i = 0; i < CH; ++i)
            #pragma unroll
            for (int e = 0; e < 4; ++e) acc[i][e] = blr[e];

        #pragma unroll 2
        for (int d = 0; d < DD; d += 4) {
            const float4 w0 = *reinterpret_cast<const float4*>(&Wl[(size_t)(d + 0) * DD + e0]);
            const float4 w1 = *reinterpret_cast<const float4*>(&Wl[(size_t)(d + 1) * DD + e0]);
            const float4 w2 = *reinterpret_cast<const float4*>(&Wl[(size_t)(d + 2) * DD + e0]);
            const float4 w3 = *reinterpret_cast<const float4*>(&Wl[(size_t)(d + 3) * DD + e0]);
            #pragma unroll
            for (int i = 0; i < CH; ++i) {
                const float4 xv = *reinterpret_cast<const float4*>(&xs[i * DD + d]);
                // d-ascending fmaf chain per (t,e): identical to r1/4/5/6 passes
                acc[i][0] = fmaf(xv.x, w0.x, acc[i][0]);
                acc[i][1] = fmaf(xv.x, w0.y, acc[i][1]);
                acc[i][2] = fmaf(xv.x, w0.z, acc[i][2]);
                acc[i][3] = fmaf(xv.x, w0.w, acc[i][3]);
                acc[i][0] = fmaf(xv.y, w1.x, acc[i][0]);
                acc[i][1] = fmaf(xv.y, w1.y, acc[i][1]);
                acc[i][2] = fmaf(xv.y, w1.z, acc[i][2]);
                acc[i][3] = fmaf(xv.y, w1.w, acc[i][3]);
                acc[i][0] = fmaf(xv.z, w2.x, acc[i][0]);
                acc[i][1] = fmaf(xv.z, w2.y, acc[i][1]);
                acc[i][2] = fmaf(xv.z, w2.z, acc[i][2]);
                acc[i][3] = fmaf(xv.z, w2.w, acc[i][3]);
                acc[i][0] = fmaf(xv.w, w3.x, acc[i][0]);
                acc[i][1] = fmaf(xv.w, w3.y, acc[i][1]);
                acc[i][2] = fmaf(xv.w, w3.z, acc[i][2]);
                acc[i][3] = fmaf(xv.w, w3.w, acc[i][3]);
            }
        }
        __syncthreads();   // compute reads done

        // LIF (identical arithmetic) + g = s?0:x -> bf16 workspace
        #pragma unroll
        for (int i = 0; i < CH; ++i) {
            const int t = tg * CH + i;
            const float4 xv = *reinterpret_cast<const float4*>(&xs[i * DD + e0]);
            float g[4];
            const float xr[4] = {xv.x, xv.y, xv.z, xv.w};
            #pragma unroll
            for (int e = 0; e < 4; ++e) {
                m[e] = m[e] + (acc[i][e] - m[e]) * 0.5f;
                const float s = (m[e] - 1.0f > 0.0f) ? 1.0f : 0.0f;
                g[e] = (s > 0.0f) ? 0.0f : xr[e];
                m[e] *= (1.0f - s);
            }
            uint2 p;
            p.x = (unsigned)f2bf(g[0]) | ((unsigned)f2bf(g[1]) << 16);
            p.y = (unsigned)f2bf(g[2]) | ((unsigned)f2bf(g[3]) << 16);
            *reinterpret_cast<uint2*>(&gws[((size_t)tok * TT + t) * DD + e0]) = p;
        }
        __syncthreads();   // g reads of xs done before next chunk staging
    }
}

// ========== Tier-1 Phase B: pure bf16 GEMM out = g @ Wr^T(bf16) + br =======
// 1 token/block, 512 thr, 8 waves = (t-half, col-quarter). No LDS, no masks.
__global__ __launch_bounds__(512, 2) void lif_phaseB3(
    const unsigned short* __restrict__ gws,  // [B*N*T, D] bf16
    const unsigned short* __restrict__ Wt,   // [D,D] bf16 transposed
    const float* __restrict__ br,            // [D]
    float* __restrict__ out)                 // [T,B,N,D]
{
    const int tid = threadIdx.x;          // 0..511
    const int tok = blockIdx.x;           // 0..2047
    const int w    = tid >> 6;            // 0..7
    const int lane = tid & 63;
    const int hB   = w & 1;               // t-half
    const int q    = w >> 1;              // col quarter (128 cols)
    const int lcol = lane & 15;
    const int lkg  = lane >> 4;           // 0..3
    const int tA   = hB * 16 + lcol;      // A row (t) this lane supplies
    const size_t st = (size_t)BB * NN * DD;
    const int colb = q * 128;

    const unsigned short* arow = &gws[((size_t)tok * TT + tA) * DD];

    f32x4 acc[8];
    #pragma unroll
    for (int nt = 0; nt < 8; ++nt) {
        const float b = br[colb + nt * 16 + lcol];
        acc[nt] = (f32x4){b, b, b, b};
    }

    #pragma unroll 1
    for (int ks = 0; ks < 16; ++ks) {
        const int kb = ks * 32 + lkg * 8;
        const short8 a = *reinterpret_cast<const short8*>(&arow[kb]);
        #pragma unroll
        for (int nt = 0; nt < 8; ++nt) {
            const int col = colb + nt * 16 + lcol;
            const short8 bf = *reinterpret_cast<const short8*>(&Wt[(size_t)col * DD + kb]);
            acc[nt] = __builtin_amdgcn_mfma_f32_16x16x32_bf16(a, bf, acc[nt], 0, 0, 0);
        }
    }

    // epilogue: C/D layout col=lane&15, row=(lane>>4)*4+r (verified r7/r10/r12)
    #pragma unroll
    for (int nt = 0; nt < 8; ++nt) {
        const int col = colb + nt * 16 + lcol;
        #pragma unroll
        for (int r = 0; r < 4; ++r) {
            const int t = hB * 16 + lkg * 4 + r;
            out[(size_t)t * st + (size_t)tok * DD + col] = acc[nt][r];
        }
    }
}

// ========== Tier-2 Phase A: GEMM1+LIF -> global bitmask (r11, 488us) =======
__global__ __launch_bounds__(128, 4) void lif_phaseA_m(
    const float* __restrict__ x, const float* __restrict__ tr_mx,
    const float* __restrict__ Wl, const float* __restrict__ bl,
    unsigned* __restrict__ gmsk)
{
    __shared__ __align__(16) float xs[CH * 256];   // 8 KB

    const int tid = threadIdx.x;
    const int tok = blockIdx.x;
    const int e0  = tid * 4;
    const size_t base = (size_t)tok * DD;
    const size_t st   = (size_t)BB * NN * DD;

    float acc[CH][4];
    float4 m4 = *reinterpret_cast<const float4*>(&tr_mx[base + e0]);
    float m[4] = {m4.x, m4.y, m4.z, m4.w};
    unsigned mc[4] = {0u, 0u, 0u, 0u};
    const float4 blv = *reinterpret_cast<const float4*>(&bl[e0]);
    const float blr[4] = {blv.x, blv.y, blv.z, blv.w};

    #pragma unroll 1
    for (int tg = 0; tg < 4; ++tg) {
        #pragma unroll
        for (int i = 0; i < CH; ++i)
            #pragma unroll
            for (int e = 0; e < 4; ++e) acc[i][e] = blr[e];

        #pragma unroll 1
        for (int h = 0; h < 2; ++h) {
            #pragma unroll
            for (int r = 0; r < 4; ++r) {
                const int flat = r * 128 + tid;
                const int row  = flat >> 6;
                const int c4   = flat & 63;
                const float4 v = *reinterpret_cast<const float4*>(
                    &x[(size_t)(tg * CH + row) * st + base + h * 256 + c4 * 4]);
                *reinterpret_cast<float4*>(&xs[row * 256 + c4 * 4]) = v;
            }
            __syncthreads();

            #pragma unroll 2
            for (int dd_ = 0; dd_ < 256; dd_ += 4) {
                const int d = h * 256 + dd_;
                const float4 w0 = *reinterpret_cast<const float4*>(&Wl[(size_t)(d + 0) * DD + e0]);
                const float4 w1 = *reinterpret_cast<const float4*>(&Wl[(size_t)(d + 1) * DD + e0]);
                const float4 w2 = *reinterpret_cast<const float4*>(&Wl[(size_t)(d + 2) * DD + e0]);
                const float4 w3 = *reinterpret_cast<const float4*>(&Wl[(size_t)(d + 3) * DD + e0]);
                #pragma unroll
                for (int i = 0; i < CH; ++i) {
                    const float4 xv = *reinterpret_cast<const float4*>(&xs[i * 256 + dd_]);
                    acc[i][0] = fmaf(xv.x, w0.x, acc[i][0]);
                    acc[i][1] = fmaf(xv.x, w0.y, acc[i][1]);
                    acc[i][2] = fmaf(xv.x, w0.z, acc[i][2]);
                    acc[i][3] = fmaf(xv.x, w0.w, acc[i][3]);
                    acc[i][0] = fmaf(xv.y, w1.x, acc[i][0]);
                    acc[i][1] = fmaf(xv.y, w1.y, acc[i][1]);
                    acc[i][2] = fmaf(xv.y, w1.z, acc[i][2]);
                    acc[i][3] = fmaf(xv.y, w1.w, acc[i][3]);
                    acc[i][0] = fmaf(xv.z, w2.x, acc[i][0]);
                    acc[i][1] = fmaf(xv.z, w2.y, acc[i][1]);
                    acc[i][2] = fmaf(xv.z, w2.z, acc[i][2]);
                    acc[i][3] = fmaf(xv.z, w2.w, acc[i][3]);
                    acc[i][0] = fmaf(xv.w, w3.x, acc[i][0]);
                    acc[i][1] = fmaf(xv.w, w3.y, acc[i][1]);
                    acc[i][2] = fmaf(xv.w, w3.z, acc[i][2]);
                    acc[i][3] = fmaf(xv.w, w3.w, acc[i][3]);
                }
            }
            __syncthreads();
        }

        #pragma unroll
        for (int i = 0; i < CH; ++i) {
            const int t = tg * CH + i;
            #pragma unroll
            for (int e = 0; e < 4; ++e) {
                m[e] = m[e] + (acc[i][e] - m[e]) * 0.5f;
                const float s = (m[e] - 1.0f > 0.0f) ? 1.0f : 0.0f;
                mc[e] |= (s > 0.0f) ? (1u << t) : 0u;
                m[e] *= (1.0f - s);
            }
        }
    }

    uint4 mv;
    mv.x = mc[0]; mv.y = mc[1]; mv.z = mc[2]; mv.w = mc[3];
    *reinterpret_cast<uint4*>(&gmsk[base + e0]) = mv;
}

// ========== Tier-2 Phase B: r12's MFMA GEMM2 (mask + x) ====================
template<bool UW>
__global__ __launch_bounds__(256, 2) void lif_phaseB2(
    const float* __restrict__ x, const float* __restrict__ Wr,
    const float* __restrict__ br, const unsigned short* __restrict__ Wt,
    const unsigned* __restrict__ gmsk, float* __restrict__ out)
{
    __shared__ __align__(16) unsigned ms[2 * DD];

    const int tid = threadIdx.x;
    const size_t st = (size_t)BB * NN * DD;
    {
        const uint4 v = *reinterpret_cast<const uint4*>(
            &gmsk[(size_t)blockIdx.x * 2 * DD + tid * 4]);
        *reinterpret_cast<uint4*>(&ms[tid * 4]) = v;
    }
    __syncthreads();

    const int wv   = tid >> 6;
    const int lane = tid & 63;
    const int qB   = wv >> 1;
    const int hB   = wv & 1;
    const int lcol = lane & 15;
    const int lkg  = lane >> 4;
    const int tA   = hB * 16 + lcol;
    const size_t baseB = (size_t)(blockIdx.x * 2 + qB) * DD;
    const unsigned* mq = &ms[qB * DD];
    const float* xrow = &x[(size_t)tA * st + baseB];

    #pragma unroll 1
    for (int pass = 0; pass < 4; ++pass) {
        const int colb = pass * 128;
        f32x4 acc[8];
        #pragma unroll
        for (int nt = 0; nt < 8; ++nt) {
            const float b = br[colb + nt * 16 + lcol];
            acc[nt] = (f32x4){b, b, b, b};
        }
        #pragma unroll 1
        for (int ks = 0; ks < 16; ++ks) {
            const int kb = ks * 32 + lkg * 8;
            const float4 x0 = *reinterpret_cast<const float4*>(&xrow[kb]);
            const float4 x1 = *reinterpret_cast<const float4*>(&xrow[kb + 4]);
            const uint4 m0 = *reinterpret_cast<const uint4*>(&mq[kb]);
            const uint4 m1 = *reinterpret_cast<const uint4*>(&mq[kb + 4]);
            short8 a;
            a[0] = (short)f2bf(((m0.x >> tA) & 1u) ? 0.0f : x0.x);
            a[1] = (short)f2bf(((m0.y >> tA) & 1u) ? 0.0f : x0.y);
            a[2] = (short)f2bf(((m0.z >> tA) & 1u) ? 0.0f : x0.z);
            a[3] = (short)f2bf(((m0.w >> tA) & 1u) ? 0.0f : x0.w);
            a[4] = (short)f2bf(((m1.x >> tA) & 1u) ? 0.0f : x1.x);
            a[5] = (short)f2bf(((m1.y >> tA) & 1u) ? 0.0f : x1.y);
            a[6] = (short)f2bf(((m1.z >> tA) & 1u) ? 0.0f : x1.z);
            a[7] = (short)f2bf(((m1.w >> tA) & 1u) ? 0.0f : x1.w);
            #pragma unroll
            for (int nt = 0; nt < 8; ++nt) {
                const int col = colb + nt * 16 + lcol;
                short8 bf;
                if (UW) {
                    bf = *reinterpret_cast<const short8*>(&Wt[(size_t)col * DD + kb]);
                } else {
                    #pragma unroll
                    for (int j = 0; j < 8; ++j)
                        bf[j] = (short)f2bf(Wr[(size_t)(kb + j) * DD + col]);
                }
                acc[nt] = __builtin_amdgcn_mfma_f32_16x16x32_bf16(a, bf, acc[nt], 0, 0, 0);
            }
        }
        #pragma unroll
        for (int nt = 0; nt < 8; ++nt) {
            const int col = colb + nt * 16 + lcol;
            #pragma unroll
            for (int r = 0; r < 4; ++r) {
                const int t = hB * 16 + lkg * 4 + r;
                out[(size_t)t * st + baseB + col] = acc[nt][r];
            }
        }
    }
}

extern "C" void kernel_launch(void* const* d_in, const int* in_sizes, int n_in,
                              void* d_out, int out_size, void* d_ws, size_t ws_size,
                              hipStream_t stream) {
    const float* x     = (const float*)d_in[0];
    const float* tr_mx = (const float*)d_in[1];
    const float* Wl    = (const float*)d_in[2];
    const float* bl    = (const float*)d_in[3];
    const float* Wr    = (const float*)d_in[4];
    const float* br    = (const float*)d_in[5];
    float* out = (float*)d_out;

    const size_t g_bytes   = (size_t)BB * NN * TT * DD * 2;   // 67.1 MB
    const size_t wt_bytes  = (size_t)DD * DD * 2;             // 512 KB
    const size_t msk_bytes = (size_t)BB * NN * DD * 4;        // 4 MB

    if (ws_size >= g_bytes + wt_bytes) {
        unsigned short* gws = (unsigned short*)d_ws;
        unsigned short* Wt  = (unsigned short*)((char*)d_ws + g_bytes);
        cast_transpose_wr<<<dim3(1024), dim3(256), 0, stream>>>(Wr, Wt);
        lif_phaseA_g<<<dim3(BB * NN), dim3(128), 0, stream>>>(x, tr_mx, Wl, bl, gws);
        lif_phaseB3<<<dim3(BB * NN), dim3(512), 0, stream>>>(gws, Wt, br, out);
    } else if (ws_size >= msk_bytes + wt_bytes) {
        unsigned* gmsk = (unsigned*)d_ws;
        unsigned short* Wt = (unsigned short*)((char*)d_ws + msk_bytes);
        cast_transpose_wr<<<dim3(1024), dim3(256), 0, stream>>>(Wr, Wt);
        lif_phaseA_m<<<dim3(BB * NN), dim3(128), 0, stream>>>(x, tr_mx, Wl, bl, gmsk);
        lif_phaseB2<true><<<dim3(BB * NN / 2), dim3(256), 0, stream>>>(x, Wr, br, Wt, gmsk, out);
    } else if (ws_size >= msk_bytes) {
        unsigned* gmsk = (unsigned*)d_ws;
        lif_phaseA_m<<<dim3(BB * NN), dim3(128), 0, stream>>>(x, tr_mx, Wl, bl, gmsk);
        lif_phaseB2<false><<<dim3(BB * NN / 2), dim3(256), 0, stream>>>(x, Wr, br, nullptr, gmsk, out);
    }
    // (ws_size < 4MB does not occur in this harness; r11/r12 confirmed >= 4.7MB)
}

// Round 14
// 626.131 us; speedup vs baseline: 1.4132x; 1.2198x over previous
//
#include <hip/hip_runtime.h>
#include <hip/hip_bf16.h>

// Decoder_21208548508049 — round 14.
// r13: phaseA 554us (Wl re-streamed 4x/block -> 8.4GB L2 ~ 243us, vs 218us FMA
// floor), phaseB 205us (9 loads per 8 MFMA; Wt streamed per token).
// Fix: token-share the weight streams.
//   Phase A: 4 tokens/block (64KB LDS) -> Wl L2 traffic /4 = 2.1GB (61us).
//            Per-token chain/LIF/g-write verbatim r13 -> spikes bit-identical.
//   Phase B: 2 tokens per wave -> 16 MFMA per 10 loads; Wt L2 /2.
//
// T=32,B=8,N=256,D=512.

#define TT 32
#define CH 8
#define BB 8
#define NN 256
#define DD 512

typedef __attribute__((ext_vector_type(8))) short short8;
typedef __attribute__((ext_vector_type(4))) float f32x4;

__device__ __forceinline__ unsigned short f2bf(float f) {
    __hip_bfloat16 h = __float2bfloat16(f);
    return *reinterpret_cast<unsigned short*>(&h);
}

// ---- pre-kernel: Wt[p][d] = bf16(Wr[d][p]) ----
__global__ void cast_transpose_wr(const float* __restrict__ Wr,
                                  unsigned short* __restrict__ Wt) {
    int idx = blockIdx.x * 256 + threadIdx.x;      // 0..262143
    int d = idx >> 9;
    int p = idx & 511;
    Wt[p * DD + d] = f2bf(Wr[idx]);
}

// ========== Tier-1 Phase A: GEMM1 (exact f32) + LIF -> g (bf16), 4 tok/blk ==
__global__ __launch_bounds__(512, 4) void lif_phaseA_g4(
    const float* __restrict__ x,      // [T,B,N,D]
    const float* __restrict__ tr_mx,  // [B,N,D]
    const float* __restrict__ Wl,     // [D,D]
    const float* __restrict__ bl,     // [D]
    unsigned short* __restrict__ gws) // [B*N*T, D] bf16: g[tok*32+t][e]
{
    __shared__ __align__(16) float xs[4 * CH * DD];   // 64 KB: 4 tokens x chunk

    const int tid = threadIdx.x;          // 0..511
    const int tq  = tid >> 7;             // token slot 0..3
    const int tl  = tid & 127;
    const int e0  = tl * 4;
    const int tok = blockIdx.x * 4 + tq;
    const size_t base = (size_t)tok * DD;
    const size_t st   = (size_t)BB * NN * DD;

    float acc[CH][4];
    float4 m4 = *reinterpret_cast<const float4*>(&tr_mx[base + e0]);
    float m[4] = {m4.x, m4.y, m4.z, m4.w};

    const float4 blv = *reinterpret_cast<const float4*>(&bl[e0]);
    const float blr[4] = {blv.x, blv.y, blv.z, blv.w};

    #pragma unroll 1
    for (int tg = 0; tg < 4; ++tg) {
        // stage x[tg*8..+7][4 tokens][0..511]: 8 float4/thread, coalesced
        #pragma unroll
        for (int r = 0; r < 8; ++r) {
            const int flat = r * 512 + tid;        // 0..4095
            const int q    = flat >> 10;           // token 0..3
            const int rem  = flat & 1023;
            const int row  = rem >> 7;             // 0..7
            const int c4   = rem & 127;
            const float4 v = *reinterpret_cast<const float4*>(
                &x[(size_t)(tg * CH + row) * st
                   + (size_t)(blockIdx.x * 4 + q) * DD + c4 * 4]);
            *reinterpret_cast<float4*>(&xs[(q * CH + row) * DD + c4 * 4]) = v;
        }
        __syncthreads();

        #pragma unroll
        for (int i = 0; i < CH; ++i)
            #pragma unroll
            for (int e = 0; e < 4; ++e) acc[i][e] = blr[e];

        const float* xsl = &xs[tq * CH * DD];   // own token's tile

        #pragma unroll 2
        for (int d = 0; d < DD; d += 4) {
            const float4 w0 = *reinterpret_cast<const float4*>(&Wl[(size_t)(d + 0) * DD + e0]);
            const float4 w1 = *reinterpret_cast<const float4*>(&Wl[(size_t)(d + 1) * DD + e0]);
            const float4 w2 = *reinterpret_cast<const float4*>(&Wl[(size_t)(d + 2) * DD + e0]);
            const float4 w3 = *reinterpret_cast<const float4*>(&Wl[(size_t)(d + 3) * DD + e0]);
            #pragma unroll
            for (int i = 0; i < CH; ++i) {
                const float4 xv = *reinterpret_cast<const float4*>(&xsl[i * DD + d]);
                // d-ascending fmaf chain per (t,e): identical to r1/4/5/6/13
                acc[i][0] = fmaf(xv.x, w0.x, acc[i][0]);
                acc[i][1] = fmaf(xv.x, w0.y, acc[i][1]);
                acc[i][2] = fmaf(xv.x, w0.z, acc[i][2]);
                acc[i][3] = fmaf(xv.x, w0.w, acc[i][3]);
                acc[i][0] = fmaf(xv.y, w1.x, acc[i][0]);
                acc[i][1] = fmaf(xv.y, w1.y, acc[i][1]);
                acc[i][2] = fmaf(xv.y, w1.z, acc[i][2]);
                acc[i][3] = fmaf(xv.y, w1.w, acc[i][3]);
                acc[i][0] = fmaf(xv.z, w2.x, acc[i][0]);
                acc[i][1] = fmaf(xv.z, w2.y, acc[i][1]);
                acc[i][2] = fmaf(xv.z, w2.z, acc[i][2]);
                acc[i][3] = fmaf(xv.z, w2.w, acc[i][3]);
                acc[i][0] = fmaf(xv.w, w3.x, acc[i][0]);
                acc[i][1] = fmaf(xv.w, w3.y, acc[i][1]);
                acc[i][2] = fmaf(xv.w, w3.z, acc[i][2]);
                acc[i][3] = fmaf(xv.w, w3.w, acc[i][3]);
            }
        }
        // (no barrier needed here: LIF/g-write only READ xs, same as compute)

        // LIF (identical arithmetic) + g = s?0:x -> bf16 workspace
        #pragma unroll
        for (int i = 0; i < CH; ++i) {
            const int t = tg * CH + i;
            const float4 xv = *reinterpret_cast<const float4*>(&xsl[i * DD + e0]);
            float g[4];
            const float xr[4] = {xv.x, xv.y, xv.z, xv.w};
            #pragma unroll
            for (int e = 0; e < 4; ++e) {
                m[e] = m[e] + (acc[i][e] - m[e]) * 0.5f;
                const float s = (m[e] - 1.0f > 0.0f) ? 1.0f : 0.0f;
                g[e] = (s > 0.0f) ? 0.0f : xr[e];
                m[e] *= (1.0f - s);
            }
            uint2 p;
            p.x = (unsigned)f2bf(g[0]) | ((unsigned)f2bf(g[1]) << 16);
            p.y = (unsigned)f2bf(g[2]) | ((unsigned)f2bf(g[3]) << 16);
            *reinterpret_cast<uint2*>(&gws[((size_t)tok * TT + t) * DD + e0]) = p;
        }
        __syncthreads();   // all xs reads done before next chunk staging
    }
}

// ========== Tier-1 Phase B: pure bf16 GEMM, 2 tokens per wave ==============
// 1024 blocks x 512 thr, 8 waves = (t-half, col-quarter), tokens {2b, 2b+1}.
__global__ __launch_bounds__(512, 2) void lif_phaseB4(
    const unsigned short* __restrict__ gws,  // [B*N*T, D] bf16
    const unsigned short* __restrict__ Wt,   // [D,D] bf16 transposed
    const float* __restrict__ br,            // [D]
    float* __restrict__ out)                 // [T,B,N,D]
{
    const int tid = threadIdx.x;          // 0..511
    const int w    = tid >> 6;            // 0..7
    const int lane = tid & 63;
    const int hB   = w & 1;               // t-half
    const int q    = w >> 1;              // col quarter (128 cols)
    const int lcol = lane & 15;
    const int lkg  = lane >> 4;           // 0..3
    const int tA   = hB * 16 + lcol;      // A row (t) this lane supplies
    const size_t st = (size_t)BB * NN * DD;
    const int colb = q * 128;
    const int tok0 = blockIdx.x * 2;

    const unsigned short* arow0 = &gws[((size_t)tok0 * TT + tA) * DD];
    const unsigned short* arow1 = &gws[((size_t)(tok0 + 1) * TT + tA) * DD];

    f32x4 acc0[8], acc1[8];
    #pragma unroll
    for (int nt = 0; nt < 8; ++nt) {
        const float b = br[colb + nt * 16 + lcol];
        acc0[nt] = (f32x4){b, b, b, b};
        acc1[nt] = (f32x4){b, b, b, b};
    }

    #pragma unroll 1
    for (int ks = 0; ks < 16; ++ks) {
        const int kb = ks * 32 + lkg * 8;
        const short8 a0 = *reinterpret_cast<const short8*>(&arow0[kb]);
        const short8 a1 = *reinterpret_cast<const short8*>(&arow1[kb]);
        #pragma unroll
        for (int nt = 0; nt < 8; ++nt) {
            const int col = colb + nt * 16 + lcol;
            const short8 bf = *reinterpret_cast<const short8*>(&Wt[(size_t)col * DD + kb]);
            acc0[nt] = __builtin_amdgcn_mfma_f32_16x16x32_bf16(a0, bf, acc0[nt], 0, 0, 0);
            acc1[nt] = __builtin_amdgcn_mfma_f32_16x16x32_bf16(a1, bf, acc1[nt], 0, 0, 0);
        }
    }

    // epilogue: C/D layout col=lane&15, row=(lane>>4)*4+r (verified r7/r10/r13)
    #pragma unroll
    for (int nt = 0; nt < 8; ++nt) {
        const int col = colb + nt * 16 + lcol;
        #pragma unroll
        for (int r = 0; r < 4; ++r) {
            const int t = hB * 16 + lkg * 4 + r;
            out[(size_t)t * st + (size_t)tok0 * DD + col]       = acc0[nt][r];
            out[(size_t)t * st + (size_t)(tok0 + 1) * DD + col] = acc1[nt][r];
        }
    }
}

// ========== Tier-2 Phase A: GEMM1+LIF -> global bitmask (r11) ==============
__global__ __launch_bounds__(128, 4) void lif_phaseA_m(
    const float* __restrict__ x, const float* __restrict__ tr_mx,
    const float* __restrict__ Wl, const float* __restrict__ bl,
    unsigned* __restrict__ gmsk)
{
    __shared__ __align__(16) float xs[CH * 256];

    const int tid = threadIdx.x;
    const int tok = blockIdx.x;
    const int e0  = tid * 4;
    const size_t base = (size_t)tok * DD;
    const size_t st   = (size_t)BB * NN * DD;

    float acc[CH][4];
    float4 m4 = *reinterpret_cast<const float4*>(&tr_mx[base + e0]);
    float m[4] = {m4.x, m4.y, m4.z, m4.w};
    unsigned mc[4] = {0u, 0u, 0u, 0u};
    const float4 blv = *reinterpret_cast<const float4*>(&bl[e0]);
    const float blr[4] = {blv.x, blv.y, blv.z, blv.w};

    #pragma unroll 1
    for (int tg = 0; tg < 4; ++tg) {
        #pragma unroll
        for (int i = 0; i < CH; ++i)
            #pragma unroll
            for (int e = 0; e < 4; ++e) acc[i][e] = blr[e];

        #pragma unroll 1
        for (int h = 0; h < 2; ++h) {
            #pragma unroll
            for (int r = 0; r < 4; ++r) {
                const int flat = r * 128 + tid;
                const int row  = flat >> 6;
                const int c4   = flat & 63;
                const float4 v = *reinterpret_cast<const float4*>(
                    &x[(size_t)(tg * CH + row) * st + base + h * 256 + c4 * 4]);
                *reinterpret_cast<float4*>(&xs[row * 256 + c4 * 4]) = v;
            }
            __syncthreads();

            #pragma unroll 2
            for (int dd_ = 0; dd_ < 256; dd_ += 4) {
                const int d = h * 256 + dd_;
                const float4 w0 = *reinterpret_cast<const float4*>(&Wl[(size_t)(d + 0) * DD + e0]);
                const float4 w1 = *reinterpret_cast<const float4*>(&Wl[(size_t)(d + 1) * DD + e0]);
                const float4 w2 = *reinterpret_cast<const float4*>(&Wl[(size_t)(d + 2) * DD + e0]);
                const float4 w3 = *reinterpret_cast<const float4*>(&Wl[(size_t)(d + 3) * DD + e0]);
                #pragma unroll
                for (int i = 0; i < CH; ++i) {
                    const float4 xv = *reinterpret_cast<const float4*>(&xs[i * 256 + dd_]);
                    acc[i][0] = fmaf(xv.x, w0.x, acc[i][0]);
                    acc[i][1] = fmaf(xv.x, w0.y, acc[i][1]);
                    acc[i][2] = fmaf(xv.x, w0.z, acc[i][2]);
                    acc[i][3] = fmaf(xv.x, w0.w, acc[i][3]);
                    acc[i][0] = fmaf(xv.y, w1.x, acc[i][0]);
                    acc[i][1] = fmaf(xv.y, w1.y, acc[i][1]);
                    acc[i][2] = fmaf(xv.y, w1.z, acc[i][2]);
                    acc[i][3] = fmaf(xv.y, w1.w, acc[i][3]);
                    acc[i][0] = fmaf(xv.z, w2.x, acc[i][0]);
                    acc[i][1] = fmaf(xv.z, w2.y, acc[i][1]);
                    acc[i][2] = fmaf(xv.z, w2.z, acc[i][2]);
                    acc[i][3] = fmaf(xv.z, w2.w, acc[i][3]);
                    acc[i][0] = fmaf(xv.w, w3.x, acc[i][0]);
                    acc[i][1] = fmaf(xv.w, w3.y, acc[i][1]);
                    acc[i][2] = fmaf(xv.w, w3.z, acc[i][2]);
                    acc[i][3] = fmaf(xv.w, w3.w, acc[i][3]);
                }
            }
            __syncthreads();
        }

        #pragma unroll
        for (int i = 0; i < CH; ++i) {
            const int t = tg * CH + i;
            #pragma unroll
            for (int e = 0; e < 4; ++e) {
                m[e] = m[e] + (acc[i][e] - m[e]) * 0.5f;
                const float s = (m[e] - 1.0f > 0.0f) ? 1.0f : 0.0f;
                mc[e] |= (s > 0.0f) ? (1u << t) : 0u;
                m[e] *= (1.0f - s);
            }
        }
    }

    uint4 mv;
    mv.x = mc[0]; mv.y = mc[1]; mv.z = mc[2]; mv.w = mc[3];
    *reinterpret_cast<uint4*>(&gmsk[base + e0]) = mv;
}

// ========== Tier-2 Phase B: r12's MFMA GEMM2 (mask + x) ====================
template<bool UW>
__global__ __launch_bounds__(256, 2) void lif_phaseB2(
    const float* __restrict__ x, const float* __restrict__ Wr,
    const float* __restrict__ br, const unsigned short* __restrict__ Wt,
    const unsigned* __restrict__ gmsk, float* __restrict__ out)
{
    __shared__ __align__(16) unsigned ms[2 * DD];

    const int tid = threadIdx.x;
    const size_t st = (size_t)BB * NN * DD;
    {
        const uint4 v = *reinterpret_cast<const uint4*>(
            &gmsk[(size_t)blockIdx.x * 2 * DD + tid * 4]);
        *reinterpret_cast<uint4*>(&ms[tid * 4]) = v;
    }
    __syncthreads();

    const int wv   = tid >> 6;
    const int lane = tid & 63;
    const int qB   = wv >> 1;
    const int hB   = wv & 1;
    const int lcol = lane & 15;
    const int lkg  = lane >> 4;
    const int tA   = hB * 16 + lcol;
    const size_t baseB = (size_t)(blockIdx.x * 2 + qB) * DD;
    const unsigned* mq = &ms[qB * DD];
    const float* xrow = &x[(size_t)tA * st + baseB];

    #pragma unroll 1
    for (int pass = 0; pass < 4; ++pass) {
        const int colb = pass * 128;
        f32x4 acc[8];
        #pragma unroll
        for (int nt = 0; nt < 8; ++nt) {
            const float b = br[colb + nt * 16 + lcol];
            acc[nt] = (f32x4){b, b, b, b};
        }
        #pragma unroll 1
        for (int ks = 0; ks < 16; ++ks) {
            const int kb = ks * 32 + lkg * 8;
            const float4 x0 = *reinterpret_cast<const float4*>(&xrow[kb]);
            const float4 x1 = *reinterpret_cast<const float4*>(&xrow[kb + 4]);
            const uint4 m0 = *reinterpret_cast<const uint4*>(&mq[kb]);
            const uint4 m1 = *reinterpret_cast<const uint4*>(&mq[kb + 4]);
            short8 a;
            a[0] = (short)f2bf(((m0.x >> tA) & 1u) ? 0.0f : x0.x);
            a[1] = (short)f2bf(((m0.y >> tA) & 1u) ? 0.0f : x0.y);
            a[2] = (short)f2bf(((m0.z >> tA) & 1u) ? 0.0f : x0.z);
            a[3] = (short)f2bf(((m0.w >> tA) & 1u) ? 0.0f : x0.w);
            a[4] = (short)f2bf(((m1.x >> tA) & 1u) ? 0.0f : x1.x);
            a[5] = (short)f2bf(((m1.y >> tA) & 1u) ? 0.0f : x1.y);
            a[6] = (short)f2bf(((m1.z >> tA) & 1u) ? 0.0f : x1.z);
            a[7] = (short)f2bf(((m1.w >> tA) & 1u) ? 0.0f : x1.w);
            #pragma unroll
            for (int nt = 0; nt < 8; ++nt) {
                const int col = colb + nt * 16 + lcol;
                short8 bf;
                if (UW) {
                    bf = *reinterpret_cast<const short8*>(&Wt[(size_t)col * DD + kb]);
                } else {
                    #pragma unroll
                    for (int j = 0; j < 8; ++j)
                        bf[j] = (short)f2bf(Wr[(size_t)(kb + j) * DD + col]);
                }
                acc[nt] = __builtin_amdgcn_mfma_f32_16x16x32_bf16(a, bf, acc[nt], 0, 0, 0);
            }
        }
        #pragma unroll
        for (int nt = 0; nt < 8; ++nt) {
            const int col = colb + nt * 16 + lcol;
            #pragma unroll
            for (int r = 0; r < 4; ++r) {
                const int t = hB * 16 + lkg * 4 + r;
                out[(size_t)t * st + baseB + col] = acc[nt][r];
            }
        }
    }
}

extern "C" void kernel_launch(void* const* d_in, const int* in_sizes, int n_in,
                              void* d_out, int out_size, void* d_ws, size_t ws_size,
                              hipStream_t stream) {
    const float* x     = (const float*)d_in[0];
    const float* tr_mx = (const float*)d_in[1];
    const float* Wl    = (const float*)d_in[2];
    const float* bl    = (const float*)d_in[3];
    const float* Wr    = (const float*)d_in[4];
    const float* br    = (const float*)d_in[5];
    float* out = (float*)d_out;

    const size_t g_bytes   = (size_t)BB * NN * TT * DD * 2;   // 67.1 MB
    const size_t wt_bytes  = (size_t)DD * DD * 2;             // 512 KB
    const size_t msk_bytes = (size_t)BB * NN * DD * 4;        // 4 MB

    if (ws_size >= g_bytes + wt_bytes) {
        unsigned short* gws = (unsigned short*)d_ws;
        unsigned short* Wt  = (unsigned short*)((char*)d_ws + g_bytes);
        cast_transpose_wr<<<dim3(1024), dim3(256), 0, stream>>>(Wr, Wt);
        lif_phaseA_g4<<<dim3(BB * NN / 4), dim3(512), 0, stream>>>(x, tr_mx, Wl, bl, gws);
        lif_phaseB4<<<dim3(BB * NN / 2), dim3(512), 0, stream>>>(gws, Wt, br, out);
    } else if (ws_size >= msk_bytes + wt_bytes) {
        unsigned* gmsk = (unsigned*)d_ws;
        unsigned short* Wt = (unsigned short*)((char*)d_ws + msk_bytes);
        cast_transpose_wr<<<dim3(1024), dim3(256), 0, stream>>>(Wr, Wt);
        lif_phaseA_m<<<dim3(BB * NN), dim3(128), 0, stream>>>(x, tr_mx, Wl, bl, gmsk);
        lif_phaseB2<true><<<dim3(BB * NN / 2), dim3(256), 0, stream>>>(x, Wr, br, Wt, gmsk, out);
    } else if (ws_size >= msk_bytes) {
        unsigned* gmsk = (unsigned*)d_ws;
        lif_phaseA_m<<<dim3(BB * NN), dim3(128), 0, stream>>>(x, tr_mx, Wl, bl, gmsk);
        lif_phaseB2<false><<<dim3(BB * NN / 2), dim3(256), 0, stream>>>(x, Wr, br, nullptr, gmsk, out);
    }
}